// Round 7
// baseline (345.635 us; speedup 1.0000x reference)
//
#include <hip/hip_runtime.h>
#include <math.h>

typedef short bf16x8 __attribute__((ext_vector_type(8)));   // 8 bf16 = 4 VGPRs
typedef float f32x4  __attribute__((ext_vector_type(4)));
typedef float f32x16 __attribute__((ext_vector_type(16)));
typedef unsigned u32x4 __attribute__((ext_vector_type(4)));

#define TEMP 20.0f

__device__ __forceinline__ ushort f2bf(float f) {
    unsigned u = __float_as_uint(f);
    u = (u + 0x7FFFu + ((u >> 16) & 1u)) >> 16;   // RNE
    return (ushort)u;
}

__device__ __forceinline__ bf16x8 cvt8(const float4* p) {
    float4 a = p[0], b = p[1];
    bf16x8 r;
    r[0] = (short)f2bf(a.x); r[1] = (short)f2bf(a.y);
    r[2] = (short)f2bf(a.z); r[3] = (short)f2bf(a.w);
    r[4] = (short)f2bf(b.x); r[5] = (short)f2bf(b.y);
    r[6] = (short)f2bf(b.z); r[7] = (short)f2bf(b.w);
    return r;
}

// ---------------------------------------------------------------------------
// prep:
//   b <  128 : w_qs -> bf16          b < 256  : w_ks -> bf16
//   b < 1056 : q    -> bf16 (800)    b < 1856 : k -> bf16 (800)
//   b < 2112 : Vt[bk][h][d][c] = V[ksrc(c)][d], ksrc = c with bits2<->3
//              swapped (PV fragment's natural k order), zero-pad ksrc>=100.
// ---------------------------------------------------------------------------
__global__ __launch_bounds__(256) void prep(const float* __restrict__ wq,
                                            const float* __restrict__ wk,
                                            const float* __restrict__ q,
                                            const float* __restrict__ k,
                                            const float* __restrict__ v,
                                            ushort* __restrict__ Wq,
                                            ushort* __restrict__ Wk,
                                            ushort* __restrict__ Aq,
                                            ushort* __restrict__ Ak,
                                            ushort* __restrict__ Vt) {
    __shared__ float T[100 * 65];
    const int b = blockIdx.x, t = threadIdx.x;
    if (b < 256) {
        const float* src = (b < 128) ? wq : wk;
        ushort* dst = (b < 128) ? Wq : Wk;
        const int idx = (b & 127) * 2048 + t * 8;
        *(bf16x8*)(dst + idx) = cvt8((const float4*)(src + idx));
        return;
    }
    if (b < 1856) {
        const float* src = (b < 1056) ? q : k;
        ushort* dst = (b < 1056) ? Aq : Ak;
        const int idx = ((b < 1056 ? b - 256 : b - 1056)) * 2048 + t * 8;
        *(bf16x8*)(dst + idx) = cvt8((const float4*)(src + idx));
        return;
    }
    const int bb = b - 1856;                // bk*8 + h
    const float* in = v + (size_t)(bb >> 3) * 51200 + (bb & 7) * 6400;
    for (int i = t; i < 6400; i += 256) T[(i >> 6) * 65 + (i & 63)] = in[i];
    __syncthreads();
    const int n = t >> 2, kc = (t & 3) * 32;
    unsigned* outw = (unsigned*)(Vt + (((size_t)bb * 64 + n) * 128 + kc));
#pragma unroll
    for (int i = 0; i < 16; ++i) {
        int c0 = kc + 2 * i, c1 = c0 + 1;
        int p0 = (c0 & ~12) | ((c0 & 4) << 1) | ((c0 & 8) >> 1);  // swap bits 2,3
        int p1 = (c1 & ~12) | ((c1 & 4) << 1) | ((c1 & 8) >> 1);
        unsigned lo = (p0 < 100) ? (unsigned)f2bf(T[p0 * 65 + n]) : 0u;
        unsigned hi = (p1 < 100) ? (unsigned)f2bf(T[p1 * 65 + n]) : 0u;
        outw[i] = lo | (hi << 16);
    }
}

// ---------------------------------------------------------------------------
// Fused projection + per-64-chunk L2 norm + bf16 store; A and W already bf16.
// C[3200,512] = A[3200,512] @ W^T. grid (200,2,2): z=0 -> q, z=1 -> k.
// Wave: 16-row M-tile x 64-col chunk; chunk = blockIdx.y*4 + wave.
// ---------------------------------------------------------------------------
__global__ __launch_bounds__(256) void proj_norm(const ushort* __restrict__ Abq,
                                                 const ushort* __restrict__ Abk,
                                                 const ushort* __restrict__ Wqb,
                                                 const ushort* __restrict__ Wkb,
                                                 ushort* __restrict__ Oq,
                                                 ushort* __restrict__ Ok) {
    const ushort* A = blockIdx.z ? Abk : Abq;
    const ushort* W = blockIdx.z ? Wkb : Wqb;
    ushort* Out = blockIdx.z ? Ok : Oq;

    const int lane = threadIdx.x & 63, w = threadIdx.x >> 6;
    const int l15 = lane & 15, quad = lane >> 4;
    const int mtile = blockIdx.x;
    const int chunk = blockIdx.y * 4 + w;
    const int m = mtile * 16 + l15;

    f32x4 acc[4];
#pragma unroll
    for (int nt = 0; nt < 4; ++nt) acc[nt] = (f32x4)(0.f);

    const ushort* arow = A + (size_t)m * 512 + quad * 8;
    const ushort* wbase = W + (size_t)(chunk * 64 + l15) * 512 + quad * 8;
#pragma unroll 2
    for (int k0 = 0; k0 < 512; k0 += 32) {
        bf16x8 af = *(const bf16x8*)(arow + k0);
#pragma unroll
        for (int nt = 0; nt < 4; ++nt) {
            bf16x8 bf = *(const bf16x8*)(wbase + nt * (16 * 512) + k0);
            acc[nt] = __builtin_amdgcn_mfma_f32_16x16x32_bf16(af, bf, acc[nt], 0, 0, 0);
        }
    }
    // C/D layout: col = l15 (+16*nt), row = quad*4 + reg. Norm over the 64 cols.
#pragma unroll
    for (int reg = 0; reg < 4; ++reg) {
        float ss = 0.f;
#pragma unroll
        for (int nt = 0; nt < 4; ++nt) ss += acc[nt][reg] * acc[nt][reg];
#pragma unroll
        for (int o = 8; o >= 1; o >>= 1) ss += __shfl_xor(ss, o);
        float inv = 1.0f / fmaxf(sqrtf(ss), 1e-12f);
        int row = mtile * 16 + quad * 4 + reg;
#pragma unroll
        for (int nt = 0; nt < 4; ++nt)
            Out[(size_t)row * 512 + chunk * 64 + nt * 16 + l15] =
                f2bf(acc[nt][reg] * inv);
    }
}

// ---------------------------------------------------------------------------
// Fused attention. Block = (bq,bk): 512 threads = 8 waves = 8 heads; 4 q-tiles
// of 32 per wave (#pragma unroll 1 — flattened pipeline miscompiled, R5).
// VGPR-diet version: P is packed to bf16 (pf[7], 28 regs, compile-time
// indexed) IMMEDIATELY after exp/sum, killing sacc (64 regs) before PV —
// peak demand drops from ~150+ to ~<130 so 2 blocks/CU fit (R3 showed the
// old structure exceeds 128; occupancy was stuck at 1 block/CU = 8 waves).
// O staged via 32KB LDS tile in two 16-row halves -> contiguous stores.
// NOTE: no min-occupancy arg in __launch_bounds__ (a (512,4) floor force-caps
// VGPR and spills MFMA accumulators -> NaN, round 3).
// ---------------------------------------------------------------------------
__global__ __launch_bounds__(512) void attn8h(const ushort* __restrict__ Pqn,
                                              const ushort* __restrict__ Pkn,
                                              const ushort* __restrict__ Vt,
                                              float* __restrict__ out) {
    __shared__ float T[8192];              // [16 q][512 d], 16B-XOR swizzled

    // XCD swizzle: 1024 blocks -> each XCD owns 4 bk values (K/V L2-resident)
    const int bid = blockIdx.x;
    const int blk = (bid & 7) * 128 + (bid >> 3);
    const int bk = blk >> 5, bq = blk & 31;

    const int t = threadIdx.x;
    const int lane = t & 63;
    const int h = t >> 6;                  // wave = head
    const int l31 = lane & 31, hi = lane >> 5;

    const ushort* Qb = Pqn + (size_t)bq * 51200 + h * 6400;
    const ushort* Kb = Pkn + (size_t)bk * 51200 + h * 6400;
    const ushort* Vb = Vt + (size_t)(bk * 8 + h) * 8192;
    const ushort* krow = Kb + l31 * 64 + hi * 8;
    const ushort* vrow = Vb + l31 * 128 + hi * 8;
    float* const outB = out + (size_t)(bk * 32 + bq) * 51200;

#pragma unroll 1
    for (int qt = 0; qt < 4; ++qt) {
        // ---- S^T = Kn @ Qn^T : M = k (4 tiles of 32), N = q (this tile) ----
        const int qr = qt * 32 + l31;
        const ushort* qrow = Qb + (qr < 100 ? qr : 99) * 64 + hi * 8;
        bf16x8 qf[4];
#pragma unroll
        for (int kc = 0; kc < 4; ++kc) qf[kc] = *(const bf16x8*)(qrow + kc * 16);

        f32x16 sacc[4];
#pragma unroll
        for (int kt = 0; kt < 4; ++kt) sacc[kt] = (f32x16)(0.f);

        __builtin_amdgcn_s_setprio(1);
#pragma unroll
        for (int kc = 0; kc < 4; ++kc) {
            bf16x8 kf[4];
#pragma unroll
            for (int kt = 0; kt < 4; ++kt)
                kf[kt] = *(const bf16x8*)(krow + kt * 2048 + kc * 16);
#pragma unroll
            for (int kt = 0; kt < 4; ++kt)
                sacc[kt] = __builtin_amdgcn_mfma_f32_32x32x16_bf16(kf[kt], qf[kc], sacc[kt], 0, 0, 0);
        }
        __builtin_amdgcn_s_setprio(0);

        // ---- softmax over k for column q = l31 -----------------------------
        // lane(hi) holds k = kt*32 + (r&3) + 8*(r>>2) + 4*hi; valid: k < 100.
        float mx0 = 0.f, mx1 = 0.f;                   // relu => max >= 0
#pragma unroll
        for (int kt = 0; kt < 3; ++kt)
#pragma unroll
            for (int r = 0; r < 16; ++r) {
                float tv = fmaxf(sacc[kt][r], 0.f);
                sacc[kt][r] = tv;
                if (r & 1) mx1 = fmaxf(mx1, tv); else mx0 = fmaxf(mx0, tv);
            }
        if (hi == 0) {
#pragma unroll
            for (int r = 0; r < 4; ++r) {
                float tv = fmaxf(sacc[3][r], 0.f);
                sacc[3][r] = tv;
                if (r & 1) mx1 = fmaxf(mx1, tv); else mx0 = fmaxf(mx0, tv);
            }
        }
#pragma unroll
        for (int r = 4; r < 16; ++r) sacc[3][r] = 0.f;
        float mx = fmaxf(mx0, mx1);
        mx = fmaxf(mx, __shfl_xor(mx, 32));
        const float mT = mx * TEMP;
        float s0 = 0.f, s1 = 0.f, s2 = 0.f, s3 = 0.f;
#pragma unroll
        for (int kt = 0; kt < 3; ++kt)
#pragma unroll
            for (int r = 0; r < 16; ++r) {
                float e = __expf(fmaf(sacc[kt][r], TEMP, -mT));
                sacc[kt][r] = e;
                if ((r & 3) == 0) s0 += e; else if ((r & 3) == 1) s1 += e;
                else if ((r & 3) == 2) s2 += e; else s3 += e;
            }
        if (hi == 0) {
#pragma unroll
            for (int r = 0; r < 4; ++r) {
                float e = __expf(fmaf(sacc[3][r], TEMP, -mT));
                sacc[3][r] = e;
                s0 += e;
            }
        } else {
#pragma unroll
            for (int r = 0; r < 4; ++r) sacc[3][r] = 0.f;
        }
        float sum = (s0 + s1) + (s2 + s3);
        sum += __shfl_xor(sum, 32);
        const float inv = 1.0f / sum;                 // >= 1, never 0

        // ---- pack P -> bf16 NOW: pf[7] (28 regs), sacc dies here -----------
        u32x4 pf[7];
#pragma unroll
        for (int ks = 0; ks < 7; ++ks) {
            const int kt = ks >> 1, tt = (ks & 1) * 8;
            unsigned d0, d1, d2, d3;
            asm("v_cvt_pk_bf16_f32 %0, %1, %2" : "=v"(d0) : "v"(sacc[kt][tt + 0]), "v"(sacc[kt][tt + 1]));
            asm("v_cvt_pk_bf16_f32 %0, %1, %2" : "=v"(d1) : "v"(sacc[kt][tt + 2]), "v"(sacc[kt][tt + 3]));
            asm("v_cvt_pk_bf16_f32 %0, %1, %2" : "=v"(d2) : "v"(sacc[kt][tt + 4]), "v"(sacc[kt][tt + 5]));
            asm("v_cvt_pk_bf16_f32 %0, %1, %2" : "=v"(d3) : "v"(sacc[kt][tt + 6]), "v"(sacc[kt][tt + 7]));
            pf[ks][0] = d0; pf[ks][1] = d1; pf[ks][2] = d2; pf[ks][3] = d3;
        }

        // ---- O^T = V^T @ P^T : M = d (2 tiles of 32), K = 112 (7 x 16) -----
        f32x16 oacc0 = (f32x16)(0.f), oacc1 = (f32x16)(0.f);
        __builtin_amdgcn_s_setprio(1);
#pragma unroll
        for (int ks = 0; ks < 7; ++ks) {
            bf16x8 p = __builtin_bit_cast(bf16x8, pf[ks]);
            bf16x8 v0 = *(const bf16x8*)(vrow + ks * 16);
            bf16x8 v1 = *(const bf16x8*)(vrow + 4096 + ks * 16);
            oacc0 = __builtin_amdgcn_mfma_f32_32x32x16_bf16(v0, p, oacc0, 0, 0, 0);
            oacc1 = __builtin_amdgcn_mfma_f32_32x32x16_bf16(v1, p, oacc1, 0, 0, 0);
        }
        __builtin_amdgcn_s_setprio(0);

        // ---- stage + stream in two 16-row halves (32KB LDS tile) -----------
        // lane's q-row = l31 -> half (l31>>4), row-in-half (l31&15).
        const int rhalf = l31 >> 4, row16 = l31 & 15;
#pragma unroll 1
        for (int half = 0; half < 2; ++half) {
            if (rhalf == half) {
                const int swz = (row16 & 7) << 4;
                char* rowp = (char*)T + row16 * 2048;
#pragma unroll
                for (int g = 0; g < 4; ++g) {
                    int cb0 = h * 256 + g * 32 + hi * 16;
                    float4 v0 = {oacc0[4 * g + 0] * inv, oacc0[4 * g + 1] * inv,
                                 oacc0[4 * g + 2] * inv, oacc0[4 * g + 3] * inv};
                    *(float4*)(rowp + (cb0 ^ swz)) = v0;
                    int cb1 = cb0 + 128;
                    float4 v1 = {oacc1[4 * g + 0] * inv, oacc1[4 * g + 1] * inv,
                                 oacc1[4 * g + 2] * inv, oacc1[4 * g + 3] * inv};
                    *(float4*)(rowp + (cb1 ^ swz)) = v1;
                }
            }
            __syncthreads();
            {
                // stream 16 complete rows (32KB, fully contiguous)
                float* gb = outB + qt * 16384 + half * 8192;
                const int nIter = (qt < 3) ? 4 : 1;   // qt=3: rows 96..99 only
                for (int i = 0; i < nIter; ++i) {
                    int off = i * 8192 + t * 16;      // byte offset in half-tile
                    int qrl = off >> 11, cb = off & 2047;
                    float4 val = *(float4*)((char*)T + qrl * 2048 + (cb ^ ((qrl & 7) << 4)));
                    *(float4*)((char*)gb + off) = val;
                }
            }
            if (qt == 3) break;                       // rows 96..99 done
            __syncthreads();                          // before next stage writes
        }
    }
}

// ---------------------------------------------------------------------------
extern "C" void kernel_launch(void* const* d_in, const int* in_sizes, int n_in,
                              void* d_out, int out_size, void* d_ws, size_t ws_size,
                              hipStream_t stream) {
    const float* q  = (const float*)d_in[0];
    const float* k  = (const float*)d_in[1];
    const float* v  = (const float*)d_in[2];
    const float* wq = (const float*)d_in[3];
    const float* wk = (const float*)d_in[4];
    float* out = (float*)d_out;

    // ws (ushort): Pqn | Pkn | Vt — proven baseline footprint.
    ushort* Pqn = (ushort*)d_ws;            // 32*51200 (+slack for row overread)
    ushort* Pkn = Pqn + 1703936;
    ushort* Vt  = Pkn + 1703936;            // 32*8*64*128

    // bf16 scratch (weights + activations) in the TAIL of d_out (210MB):
    // consumed by proj_norm, then fully overwritten by attn8h.
    ushort* tail = (ushort*)d_out + ((size_t)out_size / 2) - 3801088;
    ushort* Wqb = tail;                     // 512*512
    ushort* Wkb = Wqb + 262144;
    ushort* Abq = Wkb + 262144;             // 3200*512
    ushort* Abk = Abq + 1638400;

    prep<<<2112, 256, 0, stream>>>(wq, wk, q, k, v, Wqb, Wkb, Abq, Abk, Vt);
    proj_norm<<<dim3(200, 2, 2), 256, 0, stream>>>(Abq, Abk, Wqb, Wkb, Pqn, Pkn);
    attn8h<<<1024, 512, 0, stream>>>(Pqn, Pkn, Vt, out);
}

// Round 8
// 326.144 us; speedup vs baseline: 1.0598x; 1.0598x over previous
//
#include <hip/hip_runtime.h>
#include <math.h>

typedef short bf16x8 __attribute__((ext_vector_type(8)));   // 8 bf16 = 4 VGPRs
typedef float f32x4  __attribute__((ext_vector_type(4)));
typedef float f32x16 __attribute__((ext_vector_type(16)));
typedef unsigned u32x4 __attribute__((ext_vector_type(4)));

#define TEMP 20.0f

__device__ __forceinline__ ushort f2bf(float f) {
    unsigned u = __float_as_uint(f);
    u = (u + 0x7FFFu + ((u >> 16) & 1u)) >> 16;   // RNE
    return (ushort)u;
}

__device__ __forceinline__ bf16x8 cvt8(const float4* p) {
    float4 a = p[0], b = p[1];
    bf16x8 r;
    r[0] = (short)f2bf(a.x); r[1] = (short)f2bf(a.y);
    r[2] = (short)f2bf(a.z); r[3] = (short)f2bf(a.w);
    r[4] = (short)f2bf(b.x); r[5] = (short)f2bf(b.y);
    r[6] = (short)f2bf(b.z); r[7] = (short)f2bf(b.w);
    return r;
}

// ---------------------------------------------------------------------------
// prep:
//   b <  128 : w_qs -> bf16          b < 256  : w_ks -> bf16
//   b < 1056 : q    -> bf16 (800)    b < 1856 : k -> bf16 (800)
//   b < 2112 : Vt[bk][h][d][c] = V[ksrc(c)][d], ksrc = c with bits2<->3
//              swapped (PV fragment's natural k order), zero-pad ksrc>=100.
// ---------------------------------------------------------------------------
__global__ __launch_bounds__(256) void prep(const float* __restrict__ wq,
                                            const float* __restrict__ wk,
                                            const float* __restrict__ q,
                                            const float* __restrict__ k,
                                            const float* __restrict__ v,
                                            ushort* __restrict__ Wq,
                                            ushort* __restrict__ Wk,
                                            ushort* __restrict__ Aq,
                                            ushort* __restrict__ Ak,
                                            ushort* __restrict__ Vt) {
    __shared__ float T[100 * 65];
    const int b = blockIdx.x, t = threadIdx.x;
    if (b < 256) {
        const float* src = (b < 128) ? wq : wk;
        ushort* dst = (b < 128) ? Wq : Wk;
        const int idx = (b & 127) * 2048 + t * 8;
        *(bf16x8*)(dst + idx) = cvt8((const float4*)(src + idx));
        return;
    }
    if (b < 1856) {
        const float* src = (b < 1056) ? q : k;
        ushort* dst = (b < 1056) ? Aq : Ak;
        const int idx = ((b < 1056 ? b - 256 : b - 1056)) * 2048 + t * 8;
        *(bf16x8*)(dst + idx) = cvt8((const float4*)(src + idx));
        return;
    }
    const int bb = b - 1856;                // bk*8 + h
    const float* in = v + (size_t)(bb >> 3) * 51200 + (bb & 7) * 6400;
    for (int i = t; i < 6400; i += 256) T[(i >> 6) * 65 + (i & 63)] = in[i];
    __syncthreads();
    const int n = t >> 2, kc = (t & 3) * 32;
    unsigned* outw = (unsigned*)(Vt + (((size_t)bb * 64 + n) * 128 + kc));
#pragma unroll
    for (int i = 0; i < 16; ++i) {
        int c0 = kc + 2 * i, c1 = c0 + 1;
        int p0 = (c0 & ~12) | ((c0 & 4) << 1) | ((c0 & 8) >> 1);  // swap bits 2,3
        int p1 = (c1 & ~12) | ((c1 & 4) << 1) | ((c1 & 8) >> 1);
        unsigned lo = (p0 < 100) ? (unsigned)f2bf(T[p0 * 65 + n]) : 0u;
        unsigned hi = (p1 < 100) ? (unsigned)f2bf(T[p1 * 65 + n]) : 0u;
        outw[i] = lo | (hi << 16);
    }
}

// ---------------------------------------------------------------------------
// Fused projection + per-64-chunk L2 norm + bf16 store; A and W already bf16.
// C[3200,512] = A[3200,512] @ W^T. grid (200,2,2): z=0 -> q, z=1 -> k.
// Wave: 16-row M-tile x 64-col chunk; chunk = blockIdx.y*4 + wave.
// ---------------------------------------------------------------------------
__global__ __launch_bounds__(256) void proj_norm(const ushort* __restrict__ Abq,
                                                 const ushort* __restrict__ Abk,
                                                 const ushort* __restrict__ Wqb,
                                                 const ushort* __restrict__ Wkb,
                                                 ushort* __restrict__ Oq,
                                                 ushort* __restrict__ Ok) {
    const ushort* A = blockIdx.z ? Abk : Abq;
    const ushort* W = blockIdx.z ? Wkb : Wqb;
    ushort* Out = blockIdx.z ? Ok : Oq;

    const int lane = threadIdx.x & 63, w = threadIdx.x >> 6;
    const int l15 = lane & 15, quad = lane >> 4;
    const int mtile = blockIdx.x;
    const int chunk = blockIdx.y * 4 + w;
    const int m = mtile * 16 + l15;

    f32x4 acc[4];
#pragma unroll
    for (int nt = 0; nt < 4; ++nt) acc[nt] = (f32x4)(0.f);

    const ushort* arow = A + (size_t)m * 512 + quad * 8;
    const ushort* wbase = W + (size_t)(chunk * 64 + l15) * 512 + quad * 8;
#pragma unroll 2
    for (int k0 = 0; k0 < 512; k0 += 32) {
        bf16x8 af = *(const bf16x8*)(arow + k0);
#pragma unroll
        for (int nt = 0; nt < 4; ++nt) {
            bf16x8 bf = *(const bf16x8*)(wbase + nt * (16 * 512) + k0);
            acc[nt] = __builtin_amdgcn_mfma_f32_16x16x32_bf16(af, bf, acc[nt], 0, 0, 0);
        }
    }
    // C/D layout: col = l15 (+16*nt), row = quad*4 + reg. Norm over the 64 cols.
#pragma unroll
    for (int reg = 0; reg < 4; ++reg) {
        float ss = 0.f;
#pragma unroll
        for (int nt = 0; nt < 4; ++nt) ss += acc[nt][reg] * acc[nt][reg];
#pragma unroll
        for (int o = 8; o >= 1; o >>= 1) ss += __shfl_xor(ss, o);
        float inv = 1.0f / fmaxf(sqrtf(ss), 1e-12f);
        int row = mtile * 16 + quad * 4 + reg;
#pragma unroll
        for (int nt = 0; nt < 4; ++nt)
            Out[(size_t)row * 512 + chunk * 64 + nt * 16 + l15] =
                f2bf(acc[nt][reg] * inv);
    }
}

// ---------------------------------------------------------------------------
// Fused attention, BARRIER-FREE. Block = (bq,bk): 512 threads = 8 waves = 8
// heads, each wave fully independent. Per wave, 4 q-tiles of 32 (unroll 1):
// S^T = mfma(K,Q) -> in-register softmax -> P bf16 packed in PV loop (R6
// form; pack-early regressed, R7) -> O^T = mfma(V^T,P^T). Output transpose
// goes through a PER-WAVE PRIVATE 4KB LDS region (16 q x 64 d fp32, XOR-
// swizzled): write->read ordering is wave-local lgkmcnt, so the block-wide
// __syncthreads convoy (3-4 per tile, R4-R7) is eliminated entirely. Global
// stores: per instruction 4 x 256B full-granule segments at 2KB stride
// (16-lane contiguous each) — coalescing-efficient, unlike R2's 16B scatter.
// NOTE: no min-occupancy arg in __launch_bounds__ (a (512,4) floor force-caps
// VGPR and spills MFMA accumulators -> NaN, round 3).
// ---------------------------------------------------------------------------
__global__ __launch_bounds__(512) void attn8h(const ushort* __restrict__ Pqn,
                                              const ushort* __restrict__ Pkn,
                                              const ushort* __restrict__ Vt,
                                              float* __restrict__ out) {
    __shared__ char L[32768];              // 8 waves x 4KB private O-tiles

    // XCD swizzle: 1024 blocks -> each XCD owns 4 bk values (K/V L2-resident)
    const int bid = blockIdx.x;
    const int blk = (bid & 7) * 128 + (bid >> 3);
    const int bk = blk >> 5, bq = blk & 31;

    const int t = threadIdx.x;
    const int lane = t & 63;
    const int h = t >> 6;                  // wave = head
    const int l31 = lane & 31, hi = lane >> 5;

    const ushort* Qb = Pqn + (size_t)bq * 51200 + h * 6400;
    const ushort* Kb = Pkn + (size_t)bk * 51200 + h * 6400;
    const ushort* Vb = Vt + (size_t)(bk * 8 + h) * 8192;
    const ushort* krow = Kb + l31 * 64 + hi * 8;
    const ushort* vrow = Vb + l31 * 128 + hi * 8;
    char* const wl = L + h * 4096;         // this wave's private LDS tile
    // wave's output base: rows q (stride 2048B), cols h*256 + [0,256)B
    char* const gOutW = (char*)out + (size_t)(bk * 32 + bq) * 204800 + h * 256;

#pragma unroll 1
    for (int qt = 0; qt < 4; ++qt) {
        // ---- S^T = Kn @ Qn^T : M = k (4 tiles of 32), N = q (this tile) ----
        const int qr = qt * 32 + l31;
        const ushort* qrow = Qb + (qr < 100 ? qr : 99) * 64 + hi * 8;
        bf16x8 qf[4];
#pragma unroll
        for (int kc = 0; kc < 4; ++kc) qf[kc] = *(const bf16x8*)(qrow + kc * 16);

        f32x16 sacc[4];
#pragma unroll
        for (int kt = 0; kt < 4; ++kt) sacc[kt] = (f32x16)(0.f);

        __builtin_amdgcn_s_setprio(1);
#pragma unroll
        for (int kc = 0; kc < 4; ++kc) {
            bf16x8 kf[4];
#pragma unroll
            for (int kt = 0; kt < 4; ++kt)
                kf[kt] = *(const bf16x8*)(krow + kt * 2048 + kc * 16);
#pragma unroll
            for (int kt = 0; kt < 4; ++kt)
                sacc[kt] = __builtin_amdgcn_mfma_f32_32x32x16_bf16(kf[kt], qf[kc], sacc[kt], 0, 0, 0);
        }
        __builtin_amdgcn_s_setprio(0);

        // prefetch first V fragments (independent of softmax)
        bf16x8 vf0 = *(const bf16x8*)(vrow);          // dt=0, ks=0
        bf16x8 vf1 = *(const bf16x8*)(vrow + 4096);   // dt=1, ks=0

        // ---- softmax over k for column q = l31 -----------------------------
        // lane(hi) holds k = kt*32 + (r&3) + 8*(r>>2) + 4*hi; valid: k < 100.
        float mx0 = 0.f, mx1 = 0.f;                   // relu => max >= 0
#pragma unroll
        for (int kt = 0; kt < 3; ++kt)
#pragma unroll
            for (int r = 0; r < 16; ++r) {
                float tv = fmaxf(sacc[kt][r], 0.f);
                sacc[kt][r] = tv;
                if (r & 1) mx1 = fmaxf(mx1, tv); else mx0 = fmaxf(mx0, tv);
            }
        if (hi == 0) {
#pragma unroll
            for (int r = 0; r < 4; ++r) {
                float tv = fmaxf(sacc[3][r], 0.f);
                sacc[3][r] = tv;
                if (r & 1) mx1 = fmaxf(mx1, tv); else mx0 = fmaxf(mx0, tv);
            }
        }
#pragma unroll
        for (int r = 4; r < 16; ++r) sacc[3][r] = 0.f;
        float mx = fmaxf(mx0, mx1);
        mx = fmaxf(mx, __shfl_xor(mx, 32));
        const float mT = mx * TEMP;
        float s0 = 0.f, s1 = 0.f, s2 = 0.f, s3 = 0.f;
#pragma unroll
        for (int kt = 0; kt < 3; ++kt)
#pragma unroll
            for (int r = 0; r < 16; ++r) {
                float e = __expf(fmaf(sacc[kt][r], TEMP, -mT));
                sacc[kt][r] = e;
                if ((r & 3) == 0) s0 += e; else if ((r & 3) == 1) s1 += e;
                else if ((r & 3) == 2) s2 += e; else s3 += e;
            }
        if (hi == 0) {
#pragma unroll
            for (int r = 0; r < 4; ++r) {
                float e = __expf(fmaf(sacc[3][r], TEMP, -mT));
                sacc[3][r] = e;
                s0 += e;
            }
        } else {
#pragma unroll
            for (int r = 0; r < 4; ++r) sacc[3][r] = 0.f;
        }
        float sum = (s0 + s1) + (s2 + s3);
        sum += __shfl_xor(sum, 32);
        const float inv = 1.0f / sum;                 // >= 1, never 0

        // ---- O^T = V^T @ P^T : M = d (2 tiles of 32), K = 112 (7 x 16) -----
        // (pack interleaved with MFMA — R6 form; pack-early regressed, R7)
        f32x16 oacc0 = (f32x16)(0.f), oacc1 = (f32x16)(0.f);
        __builtin_amdgcn_s_setprio(1);
#pragma unroll
        for (int ks = 0; ks < 7; ++ks) {
            const int kt = ks >> 1, tt = (ks & 1) * 8;
            unsigned d0, d1, d2, d3;
            asm("v_cvt_pk_bf16_f32 %0, %1, %2" : "=v"(d0) : "v"(sacc[kt][tt + 0]), "v"(sacc[kt][tt + 1]));
            asm("v_cvt_pk_bf16_f32 %0, %1, %2" : "=v"(d1) : "v"(sacc[kt][tt + 2]), "v"(sacc[kt][tt + 3]));
            asm("v_cvt_pk_bf16_f32 %0, %1, %2" : "=v"(d2) : "v"(sacc[kt][tt + 4]), "v"(sacc[kt][tt + 5]));
            asm("v_cvt_pk_bf16_f32 %0, %1, %2" : "=v"(d3) : "v"(sacc[kt][tt + 6]), "v"(sacc[kt][tt + 7]));
            u32x4 pw; pw[0] = d0; pw[1] = d1; pw[2] = d2; pw[3] = d3;
            bf16x8 pf = __builtin_bit_cast(bf16x8, pw);

            bf16x8 nv0, nv1;
            if (ks < 6) {
                nv0 = *(const bf16x8*)(vrow + (ks + 1) * 16);
                nv1 = *(const bf16x8*)(vrow + 4096 + (ks + 1) * 16);
            }
            oacc0 = __builtin_amdgcn_mfma_f32_32x32x16_bf16(vf0, pf, oacc0, 0, 0, 0);
            oacc1 = __builtin_amdgcn_mfma_f32_32x32x16_bf16(vf1, pf, oacc1, 0, 0, 0);
            if (ks < 6) { vf0 = nv0; vf1 = nv1; }
        }
        __builtin_amdgcn_s_setprio(0);

        // ---- wave-private transpose + store, NO barriers -------------------
        // lane holds q-row l31 (half = l31>>4), cols d = dt*32 + 8g + 4hi + e.
        // LDS tile: [16 q][64 d] fp32 = 4KB, row stride 256B, XOR-swizzled.
        const int rhalf = l31 >> 4, row16 = l31 & 15;
        const int nhalf = (qt < 3) ? 2 : 1;           // qt=3: rows 96..99 only
#pragma unroll 1
        for (int half = 0; half < nhalf; ++half) {
            if (rhalf == half) {
                const int swz = (row16 & 7) << 4;
                char* rowp = wl + row16 * 256;
#pragma unroll
                for (int g = 0; g < 4; ++g) {
                    int cb0 = g * 32 + hi * 16;       // dt=0: byte 4*(8g+4hi)
                    float4 v0 = {oacc0[4 * g + 0] * inv, oacc0[4 * g + 1] * inv,
                                 oacc0[4 * g + 2] * inv, oacc0[4 * g + 3] * inv};
                    *(float4*)(rowp + (cb0 ^ swz)) = v0;
                    int cb1 = cb0 + 128;              // dt=1: +32 floats
                    float4 v1 = {oacc1[4 * g + 0] * inv, oacc1[4 * g + 1] * inv,
                                 oacc1[4 * g + 2] * inv, oacc1[4 * g + 3] * inv};
                    *(float4*)(rowp + (cb1 ^ swz)) = v1;
                }
            }
            // wave-local write->read: compiler orders via lgkmcnt (same wave,
            // same LDS object) — no __syncthreads needed.
            char* gb = gOutW + (size_t)(qt * 32 + half * 16) * 2048;
            const int nIter = (qt < 3) ? 4 : 1;       // qt=3: 4 rows only
            for (int i = 0; i < nIter; ++i) {
                int off = i * 1024 + lane * 16;       // linear byte off in tile
                int row = off >> 8, col = off & 255;
                float4 val = *(float4*)(wl + row * 256 + (col ^ ((row & 7) << 4)));
                *(float4*)(gb + (size_t)row * 2048 + col) = val;
            }
        }
    }
}

// ---------------------------------------------------------------------------
extern "C" void kernel_launch(void* const* d_in, const int* in_sizes, int n_in,
                              void* d_out, int out_size, void* d_ws, size_t ws_size,
                              hipStream_t stream) {
    const float* q  = (const float*)d_in[0];
    const float* k  = (const float*)d_in[1];
    const float* v  = (const float*)d_in[2];
    const float* wq = (const float*)d_in[3];
    const float* wk = (const float*)d_in[4];
    float* out = (float*)d_out;

    // ws (ushort): Pqn | Pkn | Vt — proven baseline footprint.
    ushort* Pqn = (ushort*)d_ws;            // 32*51200 (+slack for row overread)
    ushort* Pkn = Pqn + 1703936;
    ushort* Vt  = Pkn + 1703936;            // 32*8*64*128

    // bf16 scratch (weights + activations) in the TAIL of d_out (210MB):
    // consumed by proj_norm, then fully overwritten by attn8h.
    ushort* tail = (ushort*)d_out + ((size_t)out_size / 2) - 3801088;
    ushort* Wqb = tail;                     // 512*512
    ushort* Wkb = Wqb + 262144;
    ushort* Abq = Wkb + 262144;             // 3200*512
    ushort* Abk = Abq + 1638400;

    prep<<<2112, 256, 0, stream>>>(wq, wk, q, k, v, Wqb, Wkb, Abq, Abk, Vt);
    proj_norm<<<dim3(200, 2, 2), 256, 0, stream>>>(Abq, Abk, Wqb, Wkb, Pqn, Pkn);
    attn8h<<<1024, 512, 0, stream>>>(Pqn, Pkn, Vt, out);
}